// Round 11
// baseline (141.257 us; speedup 1.0000x reference)
//
#include <hip/hip_runtime.h>
#include <hip/hip_bf16.h>

// Q3 unpack: each int32 holds 10 x 3-bit fields at shifts 27,24,...,0.
// Output block k (k=0..9) along dim 0 is ((packed >> (27-3k)) & 7), int32.
//
// Self-phased streaming with COUNTED drain (T4): per k-phase, issue the 16
// nt stores of stream k, then s_waitcnt vmcnt(4) — drains to 4 outstanding,
// so the store pipe never runs empty across the phase boundary (R10's full
// vmcnt(0) drain cost ~1-2us bubble x 10 phases) — then a RAW s_barrier
// (no implicit vmcnt(0)) to keep the block's 4 waves phase-locked. Stream
// concurrency stays ~1 (+4-store tail) -> copy/fill DRAM regime.
// Byte-minimal: input read once into registers.

typedef int v4i __attribute__((ext_vector_type(4)));

constexpr int TPB = 256;
constexpr int VPT = 16;                // v4i per thread
constexpr int VPB = TPB * VPT;         // 4096 v4i = 64 KB per block

__global__ __launch_bounds__(256) void q3_unpack_kernel(
    const v4i* __restrict__ in, v4i* __restrict__ out, int stride_vec) {
    const int lane = threadIdx.x & 63;
    const int w = threadIdx.x >> 6;
    // wave w owns contiguous v4i range [base + w*1024, base + w*1024 + 1024)
    const size_t wbase = (size_t)blockIdx.x * VPB + (size_t)w * (64 * VPT) + lane;

    v4i p[VPT];
#pragma unroll
    for (int j = 0; j < VPT; ++j)
        p[j] = __builtin_nontemporal_load(&in[wbase + (size_t)j * 64]);

    __syncthreads();   // loads complete + waves aligned before write phases

#pragma unroll
    for (int k = 0; k < 10; ++k) {
        const int sh = 27 - 3 * k;
        const size_t ob = (size_t)k * (size_t)stride_vec + wbase;
#pragma unroll
        for (int j = 0; j < VPT; ++j) {
            v4i v = (p[j] >> sh) & 7;
            __builtin_nontemporal_store(v, &out[ob + (size_t)j * 64]);
        }
        // Counted drain: leave 4 tail stores in flight across the boundary,
        // then raw barrier (no implicit full drain) for wave alignment.
        asm volatile("s_waitcnt vmcnt(4)" ::: "memory");
        __builtin_amdgcn_s_barrier();
    }
}

extern "C" void kernel_launch(void* const* d_in, const int* in_sizes, int n_in,
                              void* d_out, int out_size, void* d_ws, size_t ws_size,
                              hipStream_t stream) {
    const int* packed = (const int*)d_in[0];
    int* out = (int*)d_out;

    const int n_words = in_sizes[0];     // 4096*4096 = 16,777,216
    const int nvec = n_words / 4;        // 4,194,304 v4i
    const int stride_vec = n_words / 4;  // k-block stride in v4i units

    const int blocks = nvec / VPB;       // 1024 blocks, exact fit (4/CU)

    q3_unpack_kernel<<<blocks, TPB, 0, stream>>>(
        (const v4i*)packed, (v4i*)out, stride_vec);
}

// Round 12
// 141.065 us; speedup vs baseline: 1.0014x; 1.0014x over previous
//
#include <hip/hip_runtime.h>
#include <hip/hip_bf16.h>

// Q3 unpack: each int32 holds 10 x 3-bit fields at shifts 27,24,...,0.
// Output block k (k=0..9) along dim 0 is ((packed >> (27-3k)) & 7), int32.
//
// Self-phased streaming, 2 streams per phase: 5 phases, each writing two
// 64 MB output streams (copy-like 2-stream DRAM regime, 6.3 TB/s), with
// R10's proven full drain (__syncthreads => s_waitcnt vmcnt(0)+s_barrier)
// at each boundary. Halves the number of drain bubbles vs R10 (10 -> 5)
// while keeping stream concurrency in the fast regime.
// Byte-minimal: input read once into registers.

typedef int v4i __attribute__((ext_vector_type(4)));

constexpr int TPB = 256;
constexpr int VPT = 16;                // v4i per thread
constexpr int VPB = TPB * VPT;         // 4096 v4i = 64 KB per block

__global__ __launch_bounds__(256) void q3_unpack_kernel(
    const v4i* __restrict__ in, v4i* __restrict__ out, int stride_vec) {
    const int lane = threadIdx.x & 63;
    const int w = threadIdx.x >> 6;
    // wave w owns contiguous v4i range [base + w*1024, base + w*1024 + 1024)
    const size_t wbase = (size_t)blockIdx.x * VPB + (size_t)w * (64 * VPT) + lane;

    v4i p[VPT];
#pragma unroll
    for (int j = 0; j < VPT; ++j)
        p[j] = __builtin_nontemporal_load(&in[wbase + (size_t)j * 64]);

    __syncthreads();   // loads complete + waves aligned before write phases

#pragma unroll
    for (int ph = 0; ph < 5; ++ph) {
        const int k0 = 2 * ph;
#pragma unroll
        for (int kk = 0; kk < 2; ++kk) {
            const int k = k0 + kk;
            const int sh = 27 - 3 * k;
            const size_t ob = (size_t)k * (size_t)stride_vec + wbase;
#pragma unroll
            for (int j = 0; j < VPT; ++j) {
                v4i v = (p[j] >> sh) & 7;
                __builtin_nontemporal_store(v, &out[ob + (size_t)j * 64]);
            }
        }
        // Full drain + barrier at the phase boundary (R10's proven combo).
        __syncthreads();
    }
}

extern "C" void kernel_launch(void* const* d_in, const int* in_sizes, int n_in,
                              void* d_out, int out_size, void* d_ws, size_t ws_size,
                              hipStream_t stream) {
    const int* packed = (const int*)d_in[0];
    int* out = (int*)d_out;

    const int n_words = in_sizes[0];     // 4096*4096 = 16,777,216
    const int nvec = n_words / 4;        // 4,194,304 v4i
    const int stride_vec = n_words / 4;  // k-block stride in v4i units

    const int blocks = nvec / VPB;       // 1024 blocks, exact fit (4/CU)

    q3_unpack_kernel<<<blocks, TPB, 0, stream>>>(
        (const v4i*)packed, (v4i*)out, stride_vec);
}

// Round 13
// 121.078 us; speedup vs baseline: 1.1667x; 1.1651x over previous
//
#include <hip/hip_runtime.h>
#include <hip/hip_bf16.h>

// Q3 unpack: each int32 holds 10 x 3-bit fields at shifts 27,24,...,0.
// Output block k (k=0..9) along dim 0 is ((packed >> (27-3k)) & 7), int32.
//
// CU-pure self-phased streaming: ONE 1024-thread block per CU (256 blocks,
// 16 waves/CU = same occupancy as the 4x256 config, isolating alignment).
// __syncthreads() now phase-locks the ENTIRE CU, so each CU emits exactly
// one write stream per phase (R10's 4 independent blocks/CU still mixed ~4
// streams at the controller). Full drain at each boundary (purity beats
// bubble: R11/R12 both regressed with mixing). Byte-minimal: read once.

typedef int v4i __attribute__((ext_vector_type(4)));

constexpr int TPB = 1024;
constexpr int VPT = 16;                // v4i per thread
constexpr int VPB = TPB * VPT;         // 16384 v4i = 256 KB per block

__global__ __launch_bounds__(1024) void q3_unpack_kernel(
    const v4i* __restrict__ in, v4i* __restrict__ out, int stride_vec) {
    const int lane = threadIdx.x & 63;
    const int w = threadIdx.x >> 6;    // 16 waves
    // wave w owns contiguous v4i range [base + w*1024, base + w*1024 + 1024)
    const size_t wbase = (size_t)blockIdx.x * VPB + (size_t)w * (64 * VPT) + lane;

    v4i p[VPT];
#pragma unroll
    for (int j = 0; j < VPT; ++j)
        p[j] = __builtin_nontemporal_load(&in[wbase + (size_t)j * 64]);

    __syncthreads();   // loads complete + all 16 waves aligned

#pragma unroll
    for (int k = 0; k < 10; ++k) {
        const int sh = 27 - 3 * k;
        const size_t ob = (size_t)k * (size_t)stride_vec + wbase;
#pragma unroll
        for (int j = 0; j < VPT; ++j) {
            v4i v = (p[j] >> sh) & 7;
            __builtin_nontemporal_store(v, &out[ob + (size_t)j * 64]);
        }
        // Full drain + CU-wide barrier: one pure stream per CU per phase.
        __syncthreads();
    }
}

extern "C" void kernel_launch(void* const* d_in, const int* in_sizes, int n_in,
                              void* d_out, int out_size, void* d_ws, size_t ws_size,
                              hipStream_t stream) {
    const int* packed = (const int*)d_in[0];
    int* out = (int*)d_out;

    const int n_words = in_sizes[0];     // 4096*4096 = 16,777,216
    const int nvec = n_words / 4;        // 4,194,304 v4i
    const int stride_vec = n_words / 4;  // k-block stride in v4i units

    const int blocks = nvec / VPB;       // 256 blocks = 1 per CU

    q3_unpack_kernel<<<blocks, TPB, 0, stream>>>(
        (const v4i*)packed, (v4i*)out, stride_vec);
}

// Round 14
// 120.715 us; speedup vs baseline: 1.1702x; 1.0030x over previous
//
#include <hip/hip_runtime.h>
#include <hip/hip_bf16.h>

// Q3 unpack: each int32 holds 10 x 3-bit fields at shifts 27,24,...,0.
// Output block k (k=0..9) along dim 0 is ((packed >> (27-3k)) & 7), int32.
//
// CU-pure phased streaming (R13 structure: one 1024-thread block per CU,
// 16 waves phase-locked, one pure write stream per CU per phase) with a
// COUNTED boundary drain: s_waitcnt vmcnt(4) + raw s_barrier leaves each
// wave's 4 tail stores in flight across the boundary so the store pipe
// never fully empties (R13's __syncthreads = vmcnt(0) drain bubble ~1us
// x 10 phases). In the CU-pure regime the tail mixes only with this CU's
// own next stream for a brief window. No boundary after the final phase.

typedef int v4i __attribute__((ext_vector_type(4)));

constexpr int TPB = 1024;
constexpr int VPT = 16;                // v4i per thread
constexpr int VPB = TPB * VPT;         // 16384 v4i = 256 KB per block

__global__ __launch_bounds__(1024) void q3_unpack_kernel(
    const v4i* __restrict__ in, v4i* __restrict__ out, int stride_vec) {
    const int lane = threadIdx.x & 63;
    const int w = threadIdx.x >> 6;    // 16 waves
    const size_t wbase = (size_t)blockIdx.x * VPB + (size_t)w * (64 * VPT) + lane;

    v4i p[VPT];
#pragma unroll
    for (int j = 0; j < VPT; ++j)
        p[j] = __builtin_nontemporal_load(&in[wbase + (size_t)j * 64]);

    __syncthreads();   // loads complete + all 16 waves aligned

#pragma unroll
    for (int k = 0; k < 10; ++k) {
        const int sh = 27 - 3 * k;
        const size_t ob = (size_t)k * (size_t)stride_vec + wbase;
#pragma unroll
        for (int j = 0; j < VPT; ++j) {
            v4i v = (p[j] >> sh) & 7;
            __builtin_nontemporal_store(v, &out[ob + (size_t)j * 64]);
        }
        if (k < 9) {
            // Counted drain: keep 4 tail stores in flight across the
            // boundary; raw barrier (no implicit vmcnt(0)) re-aligns waves.
            asm volatile("s_waitcnt vmcnt(4)" ::: "memory");
            __builtin_amdgcn_s_barrier();
        }
    }
}

extern "C" void kernel_launch(void* const* d_in, const int* in_sizes, int n_in,
                              void* d_out, int out_size, void* d_ws, size_t ws_size,
                              hipStream_t stream) {
    const int* packed = (const int*)d_in[0];
    int* out = (int*)d_out;

    const int n_words = in_sizes[0];     // 4096*4096 = 16,777,216
    const int nvec = n_words / 4;        // 4,194,304 v4i
    const int stride_vec = n_words / 4;  // k-block stride in v4i units

    const int blocks = nvec / VPB;       // 256 blocks = 1 per CU

    q3_unpack_kernel<<<blocks, TPB, 0, stream>>>(
        (const v4i*)packed, (v4i*)out, stride_vec);
}